// Round 8
// baseline (76.059 us; speedup 1.0000x reference)
//
#include <hip/hip_runtime.h>
#include <math.h>

// Problem constants (B=8, P=64, V=32, N_TH1=30 -> D=1626)
#define NBP 512          // B*P
#define VV 32
#define DD 1626
#define DHALF 813        // directions per block (2 halves)

// Output layout (flat float32, concatenated in return order)
#define O_POINTS 0                         // (8,64*1626,3)  = 2497536
#define O_DIRH   2497536                   // (8,64,1626,4)  = 3330048
#define O_OVER   5827584                   // (8,64,1)       = 512
#define O_RETR   5828096                   // (8,64,1)       = 512
#define O_MEAN   5828608                   // (8,64,3)       = 1536
#define O_LOCAL  5830144                   // (8,64,32,3)    = 49152

#define L10_2 0.3010299956639812f    // log10(2)
#define L2_10 3.321928094887362f     // log2(10)
#define LH_MIN -66.43856189774725f   // log2(1e-20)

__device__ __forceinline__ float fexp2(float x) {
  return __builtin_amdgcn_exp2f(x);    // raw v_exp_f32
}

// inline direction via hardware v_sin/v_cos
__device__ __forceinline__ void make_dir_fast(int d, float& x, float& y, float& z) {
  if (d < 1624) {
    const int i1 = d / 58 + 1;        // 1..28
    const int i2 = d - (i1 - 1) * 58; // 0..57
    const float STEP = 0.10833078115826873f;        // pi/29
    const float th1 = -1.5707963267948966f + (float)i1 * STEP;
    const float th2 = -3.14159265358979323846f + (float)i2 * STEP;
    const float s1 = __sinf(th1);
    const float c1 = __cosf(th1);
    const float s2 = __sinf(th2);
    const float c2 = __cosf(th2);
    x = c1 * c2; y = c1 * s2; z = s1;
  } else if (d == 1624) {             // pole th1=-pi/2 (numpy f64->f32 values)
    x = -6.123234e-17f; y = -7.49880e-33f; z = -1.0f;
  } else {                            // pole th1=+pi/2
    x = -6.123234e-17f; y = -7.49880e-33f; z = 1.0f;
  }
}

// SGPR broadcast: v_readlane_b32 -> scalar register, bit-exact
#define RL(x, i) __uint_as_float(__builtin_amdgcn_readlane(__float_as_uint(x), (i)))

// one 4-vertex chunk of local_v into named scalars (wave-uniform)
#define DECL_CHUNK(b)                                                       \
  const float cx_##b##_0 = RL(lvx, 4*b+0), cx_##b##_1 = RL(lvx, 4*b+1),     \
              cx_##b##_2 = RL(lvx, 4*b+2), cx_##b##_3 = RL(lvx, 4*b+3);     \
  const float cy_##b##_0 = RL(lvy, 4*b+0), cy_##b##_1 = RL(lvy, 4*b+1),     \
              cy_##b##_2 = RL(lvy, 4*b+2), cy_##b##_3 = RL(lvy, 4*b+3);     \
  const float cz_##b##_0 = RL(lvz, 4*b+0), cz_##b##_1 = RL(lvz, 4*b+1),     \
              cz_##b##_2 = RL(lvz, 4*b+2), cz_##b##_3 = RL(lvz, 4*b+3);

// MERGED chunk: z once per element -> zmax, w (A=0 speculated), s, a.
// Bit-identical to the two-pass version when kc==0 (fmaf(pm1,l,0.0f) ==
// fmaf(pm1,l,A) at A=+0; z expressions and accumulation order unchanged).
#define MCH(b) {                                                            \
  float z0 = fmaxf(fmaf(cx_##b##_0, dx, fmaf(cy_##b##_0, dy, cz_##b##_0 * dz)), 0.f); \
  float z1 = fmaxf(fmaf(cx_##b##_1, dx, fmaf(cy_##b##_1, dy, cz_##b##_1 * dz)), 0.f); \
  float z2 = fmaxf(fmaf(cx_##b##_2, dx, fmaf(cy_##b##_2, dy, cz_##b##_2 * dz)), 0.f); \
  float z3 = fmaxf(fmaf(cx_##b##_3, dx, fmaf(cy_##b##_3, dy, cz_##b##_3 * dz)), 0.f); \
  zm0 = fmaxf(zm0, z0); zm1 = fmaxf(zm1, z1);                               \
  zm2 = fmaxf(zm2, z2); zm3 = fmaxf(zm3, z3);                               \
  float w0 = fexp2(fmaf(pm1, __log2f(z0), 0.0f));                           \
  float w1 = fexp2(fmaf(pm1, __log2f(z1), 0.0f));                           \
  float w2 = fexp2(fmaf(pm1, __log2f(z2), 0.0f));                           \
  float w3 = fexp2(fmaf(pm1, __log2f(z3), 0.0f));                           \
  s0 += w0 * z0;  s1 += w1 * z1;                                            \
  s2 += w2 * z2;  s3 += w3 * z3;                                            \
  ax = fmaf(w0, cx_##b##_0, fmaf(w1, cx_##b##_1, fmaf(w2, cx_##b##_2, fmaf(w3, cx_##b##_3, ax)))); \
  ay = fmaf(w0, cy_##b##_0, fmaf(w1, cy_##b##_1, fmaf(w2, cy_##b##_2, fmaf(w3, cy_##b##_3, ay)))); \
  az = fmaf(w0, cz_##b##_0, fmaf(w1, cz_##b##_1, fmaf(w2, cz_##b##_2, fmaf(w3, cz_##b##_3, az)))); }

// No LDS, no barriers; uncapped allocator (every capped config spilled).
__global__ __launch_bounds__(256) void spt_kernel(
    const float* __restrict__ vertices,
    const float* __restrict__ smooth,
    float* __restrict__ out)
{
  const int bp   = blockIdx.x;   // 0..511
  const int half = blockIdx.y;   // 0..1
  const int tid  = threadIdx.x;

  const int dbase = half * DHALF;

  // ---- wave-redundant mean via shuffle (lane i holds vertex i&31) ----
  const int v = tid & 31;
  const float* vp = vertices + bp * (VV * 3) + v * 3;
  const float vx = vp[0], vy = vp[1], vz = vp[2];
  float sx = vx, sy = vy, sz = vz;
#pragma unroll
  for (int m = 16; m >= 1; m >>= 1) {
    sx += __shfl_xor(sx, m);
    sy += __shfl_xor(sy, m);
    sz += __shfl_xor(sz, m);
  }
  const float mx = sx * (1.0f / 32.0f);
  const float my = sy * (1.0f / 32.0f);
  const float mz = sz * (1.0f / 32.0f);

  const float lvx = vx - mx;
  const float lvy = vy - my;
  const float lvz = vz - mz;

  // broadcast all 96 local_v scalars (replaces LDS tile entirely)
  DECL_CHUNK(0) DECL_CHUNK(1) DECL_CHUNK(2) DECL_CHUNK(3)
  DECL_CHUNK(4) DECL_CHUNK(5) DECL_CHUNK(6) DECL_CHUNK(7)

  // ---- side outputs (once, by half 1) ----
  if (half == 1) {
    if (tid < VV) {
      out[O_LOCAL + bp * (VV * 3) + tid * 3 + 0] = lvx;
      out[O_LOCAL + bp * (VV * 3) + tid * 3 + 1] = lvy;
      out[O_LOCAL + bp * (VV * 3) + tid * 3 + 2] = lvz;
    }
    if (tid == 96) {
      out[O_MEAN + bp * 3 + 0] = mx;
      out[O_MEAN + bp * 3 + 1] = my;
      out[O_MEAN + bp * 3 + 2] = mz;
      out[O_OVER + bp] = 0.f;
      out[O_RETR + bp] = 0.f;
    }
  }

  const float p     = smooth[bp];
  const float inv_p = 1.0f / p;
  const float pm1   = p - 1.0f;
  const float plt   = p * L10_2;

  // rolled outer loop (code footprint /4 vs 4x macro expansion)
#pragma unroll 1
  for (int rep = 0; rep < 4; ++rep) {
    const int idx = rep * 256 + tid;
    if (idx >= DHALF) break;           // only rep 3 (45 threads survive)
    const int d = dbase + idx;
    float dx, dy, dz;
    make_dir_fast(d, dx, dy, dz);

    // ---- single merged pass, speculating kc == 0 ----
    float zm0 = 0.f, zm1 = 0.f, zm2 = 0.f, zm3 = 0.f;
    float s0 = 0.f, s1 = 0.f, s2 = 0.f, s3 = 0.f;
    float ax = 0.f, ay = 0.f, az = 0.f;
    MCH(0) MCH(1) MCH(2) MCH(3) MCH(4) MCH(5) MCH(6) MCH(7)
    const float zmax = fmaxf(fmaxf(zm0, zm1), fmaxf(zm2, zm3));

    float kcl = 0.f;
    const float expo = __log2f(zmax) * plt;
    if (expo < -20.f) {
      // ---- rare rescale slow path (~never for this data): redo with
      //      A = p*kcl, same 4-wide accumulator order -> bit-identical
      //      to the two-pass reference kernel for kc != 0 ----
      const float kc = fminf(fmaxf(ceilf((-15.f - expo) * inv_p), 0.f), 20.f);
      kcl = kc * L2_10;
      const float A = p * kcl;
      s0 = s1 = s2 = s3 = 0.f;
      ax = ay = az = 0.f;
#pragma unroll 1
      for (int j = 0; j < 8; ++j) {
        const float X0 = RL(lvx, 4*j+0), X1 = RL(lvx, 4*j+1),
                    X2 = RL(lvx, 4*j+2), X3 = RL(lvx, 4*j+3);
        const float Y0 = RL(lvy, 4*j+0), Y1 = RL(lvy, 4*j+1),
                    Y2 = RL(lvy, 4*j+2), Y3 = RL(lvy, 4*j+3);
        const float Z0 = RL(lvz, 4*j+0), Z1 = RL(lvz, 4*j+1),
                    Z2 = RL(lvz, 4*j+2), Z3 = RL(lvz, 4*j+3);
        float z0 = fmaxf(fmaf(X0, dx, fmaf(Y0, dy, Z0 * dz)), 0.f);
        float z1 = fmaxf(fmaf(X1, dx, fmaf(Y1, dy, Z1 * dz)), 0.f);
        float z2 = fmaxf(fmaf(X2, dx, fmaf(Y2, dy, Z2 * dz)), 0.f);
        float z3 = fmaxf(fmaf(X3, dx, fmaf(Y3, dy, Z3 * dz)), 0.f);
        float w0 = fexp2(fmaf(pm1, __log2f(z0), A));
        float w1 = fexp2(fmaf(pm1, __log2f(z1), A));
        float w2 = fexp2(fmaf(pm1, __log2f(z2), A));
        float w3 = fexp2(fmaf(pm1, __log2f(z3), A));
        s0 += w0 * z0;  s1 += w1 * z1;
        s2 += w2 * z2;  s3 += w3 * z3;
        ax = fmaf(w0, X0, fmaf(w1, X1, fmaf(w2, X2, fmaf(w3, X3, ax))));
        ay = fmaf(w0, Y0, fmaf(w1, Y1, fmaf(w2, Y2, fmaf(w3, Y3, ay))));
        az = fmaf(w0, Z0, fmaf(w1, Z1, fmaf(w2, Z2, fmaf(w3, Z3, az))));
      }
    }
    const float ssum = (s0 + s1) + (s2 + s3);

    float lh = LH_MIN, C2 = 0.f;
    if (ssum > 0.f) {
      lh = inv_p * __log2f(ssum);
      C2 = fexp2(-fmaf(pm1, lh, kcl));
    }

    const int pbase = bp * DD + d;
    out[O_POINTS + pbase * 3 + 0] = fmaf(C2, ax, mx);
    out[O_POINTS + pbase * 3 + 1] = fmaf(C2, ay, my);
    out[O_POINTS + pbase * 3 + 2] = fmaf(C2, az, mz);

    float4 dvh = make_float4(dx, dy, dz, fexp2(lh - kcl));
    ((float4*)(out + O_DIRH))[pbase] = dvh;
  }
}

extern "C" void kernel_launch(void* const* d_in, const int* in_sizes, int n_in,
                              void* d_out, int out_size, void* d_ws, size_t ws_size,
                              hipStream_t stream) {
  const float* vertices = (const float*)d_in[0];  // (8,64,32,3) f32
  const float* smooth   = (const float*)d_in[1];  // (8,64) f32
  float* out = (float*)d_out;

  spt_kernel<<<dim3(NBP, 2), 256, 0, stream>>>(vertices, smooth, out);
}